// Round 12
// baseline (120.161 us; speedup 1.0000x reference)
//
#include <hip/hip_runtime.h>

// LinearAttentionSVAR: B=2, L=2048, D=1024, H=16, d=64.
// Round 12: 5 launches (prep eliminated).
//  - qkv_gemm: reads X/Wq/Wk/Wv fp32 directly; reg-staged convert
//    (8 fp32 loads -> f2bf -> ds_write_b128) into the proven row-pair-fused
//    swizzled LDS layout; 2 bufs (32KB); loads for t+2 in flight across raw
//    s_barriers (only lgkmcnt drained).
//  - prefix_fold: fold blocks compute Bm inline (LDS fp32) and convert Wc
//    in-register; prefix blocks unchanged.
//  - state_chunk / chunk_attn / out_gemm: round-10 verbatim.

#define DEV static __device__ __forceinline__

typedef unsigned short u16;
typedef unsigned long long u64;
typedef __attribute__((ext_vector_type(4))) float f32x4;
typedef __attribute__((ext_vector_type(8))) short bf16x8;

DEV u16 f2bf(float f){
  union { float f; unsigned u; } v; v.f = f;
  unsigned r = v.u + 0x7FFFu + ((v.u >> 16) & 1u);
  return (u16)(r >> 16);
}

DEV void store_val(float* p, float v){ *p = v; }
DEV void store_val(u16* p, float v){ *p = f2bf(v); }

DEV void gload16(const void* g, void* l){
  __builtin_amdgcn_global_load_lds((const __attribute__((address_space(1))) void*)g,
                                   (__attribute__((address_space(3))) void*)l, 16, 0, 0);
}

// ---------------- qkv: fp32-input GEMM with reg-staged cvt ----------------
// C[128,128](bf16) = cvt(A[128,1024] fp32) @ cvt(W[128,1024] fp32)^T
__global__ __launch_bounds__(256) void qkv_gemm(
    const float* __restrict__ X,
    const float* __restrict__ Wq, const float* __restrict__ Wk, const float* __restrict__ Wv,
    u16* __restrict__ Q, u16* __restrict__ Ko, u16* __restrict__ V)
{
  __shared__ __align__(16) u16 L[2][8192];   // 32 KB
  int sel = blockIdx.y >> 3, byl = blockIdx.y & 7;
  const float* W = sel == 0 ? Wq : sel == 1 ? Wk : Wv;
  u16* C = sel == 0 ? Q : sel == 1 ? Ko : V;
  const int bx = blockIdx.x;
  const int tid = threadIdx.x;
  const int wid = tid >> 6, lane = tid & 63;
  const int wr = wid >> 1, wc = wid & 1;
  const int lr = lane & 15, lq = lane >> 4;

  // pre-swizzled source coords (row-pair-fused layout, verified r6-r10):
  // physical elem (row,k): (row>>1)*64 + cphys*8 + (k&7),
  //   cphys = ((k>>3) | ((row&1)<<2)) ^ ((row>>1)&7); staging is linear tid*8.
  const int p0 = tid >> 3, p1 = 32 + (tid >> 3);
  const int cl0 = (tid & 7) ^ (p0 & 7);
  const int cl1 = (tid & 7) ^ (p1 & 7);
  const int srow0 = 2 * p0 + (cl0 >> 2), skc0 = (cl0 & 3) * 8;
  const int srow1 = 2 * p1 + (cl1 >> 2), skc1 = (cl1 & 3) * 8;

  const float* A0 = X + (size_t)(bx * 128 + srow0) * 1024 + skc0;
  const float* A1 = X + (size_t)(bx * 128 + srow1) * 1024 + skc1;
  const float* W0 = W + (size_t)(byl * 128 + srow0) * 1024 + skc0;
  const float* W1 = W + (size_t)(byl * 128 + srow1) * 1024 + skc1;

  float4 r0, r1, r2, r3, r4, r5, r6, r7;
  auto issue = [&](int kt){
    r0 = *(const float4*)(A0 + kt * 32);  r1 = *(const float4*)(A0 + kt * 32 + 4);
    r2 = *(const float4*)(A1 + kt * 32);  r3 = *(const float4*)(A1 + kt * 32 + 4);
    r4 = *(const float4*)(W0 + kt * 32);  r5 = *(const float4*)(W0 + kt * 32 + 4);
    r6 = *(const float4*)(W1 + kt * 32);  r7 = *(const float4*)(W1 + kt * 32 + 4);
  };
  auto writebuf = [&](u16* Lb){
    float4 g[8] = {r0, r1, r2, r3, r4, r5, r6, r7};
#pragma unroll
    for(int q = 0; q < 4; q++){
      u16 h[8] __attribute__((aligned(16)));
      float4 x0 = g[q * 2], x1 = g[q * 2 + 1];
      h[0] = f2bf(x0.x); h[1] = f2bf(x0.y); h[2] = f2bf(x0.z); h[3] = f2bf(x0.w);
      h[4] = f2bf(x1.x); h[5] = f2bf(x1.y); h[6] = f2bf(x1.z); h[7] = f2bf(x1.w);
      *(int4*)&Lb[q * 2048 + tid * 8] = *(const int4*)h;
    }
  };

  const int nt = 32;
  f32x4 acc[4][4] = {};
  issue(0);
  writebuf(L[0]);        // reg-dep waits loads(0)
  issue(1);              // in flight across prologue barrier
  asm volatile("s_waitcnt lgkmcnt(0)" ::: "memory");
  __builtin_amdgcn_s_barrier();

  for(int t = 0; t < nt; t++){
    const u16* Lb = L[t & 1];
    bf16x8 af[4], bfr[4];
#pragma unroll
    for(int i = 0; i < 4; i++){
      int row = wr * 64 + i * 16 + lr;
      int rh = row >> 1;
      int cph = (lq | ((row & 1) << 2)) ^ (rh & 7);
      af[i] = *(const bf16x8*)&Lb[rh * 64 + cph * 8];
    }
#pragma unroll
    for(int j = 0; j < 4; j++){
      int row = wc * 64 + j * 16 + lr;
      int rh = row >> 1;
      int cph = (lq | ((row & 1) << 2)) ^ (rh & 7);
      bfr[j] = *(const bf16x8*)&Lb[4096 + rh * 64 + cph * 8];
    }
#pragma unroll
    for(int i = 0; i < 4; i++)
#pragma unroll
      for(int j = 0; j < 4; j++)
        acc[i][j] = __builtin_amdgcn_mfma_f32_16x16x32_bf16(af[i], bfr[j], acc[i][j], 0, 0, 0);
    __builtin_amdgcn_s_barrier();            // all waves done reading L[t&1]
    if(t + 1 < nt){
      writebuf(L[(t + 1) & 1]);              // reg-dep waits loads(t+1)
      if(t + 2 < nt) issue(t + 2);           // fly across barriers + next compute
      asm volatile("s_waitcnt lgkmcnt(0)" ::: "memory");
      __builtin_amdgcn_s_barrier();          // writes visible before next compute
    }
  }
#pragma unroll
  for(int i = 0; i < 4; i++)
#pragma unroll
    for(int j = 0; j < 4; j++)
#pragma unroll
      for(int r = 0; r < 4; r++){
        int row = bx * 128 + wr * 64 + i * 16 + lq * 4 + r;
        int col = byl * 128 + wc * 64 + j * 16 + lr;
        C[(size_t)row * 1024 + col] = f2bf(acc[i][j][r]);
      }
}

// ---------------- out_gemm: depth-3 bf16 body (round-10 verbatim) ----------------
__global__ __launch_bounds__(256) void out_gemm(
    const u16* __restrict__ Yb, const u16* __restrict__ Wcpb, float* __restrict__ out)
{
  __shared__ u16 L[4][8192];
  const int bx = blockIdx.x, by = blockIdx.y;
  const int K = 1024, N = 1024;
  const int tid = threadIdx.x;
  const int wid = tid >> 6, lane = tid & 63;
  const int wr = wid >> 1, wc = wid & 1;
  const int lr = lane & 15, lq = lane >> 4;
  const u16* Ag = Yb + (size_t)(bx * 128) * K;
  const u16* Wg = Wcpb + (size_t)(by * 128) * K;

  const int p0 = tid >> 3, p1 = 32 + (tid >> 3);
  const int cl0 = (tid & 7) ^ (p0 & 7);
  const int cl1 = (tid & 7) ^ (p1 & 7);
  const int srow0 = 2 * p0 + (cl0 >> 2), skc0 = (cl0 & 3) * 8;
  const int srow1 = 2 * p1 + (cl1 >> 2), skc1 = (cl1 & 3) * 8;

  auto stagef = [&](int kt, int buf){
    gload16(Ag + (size_t)srow0 * K + kt * 32 + skc0, &L[buf][tid * 8]);
    gload16(Ag + (size_t)srow1 * K + kt * 32 + skc1, &L[buf][2048 + tid * 8]);
    gload16(Wg + (size_t)srow0 * K + kt * 32 + skc0, &L[buf][4096 + tid * 8]);
    gload16(Wg + (size_t)srow1 * K + kt * 32 + skc1, &L[buf][6144 + tid * 8]);
  };

  const int nt = K >> 5;
  f32x4 acc[4][4] = {};
  stagef(0, 0);
  stagef(1, 1);
  stagef(2, 2);
  for(int t = 0; t < nt; t++){
    if(t < nt - 2)       asm volatile("s_waitcnt vmcnt(8)" ::: "memory");
    else if(t == nt - 2) asm volatile("s_waitcnt vmcnt(4)" ::: "memory");
    else                 asm volatile("s_waitcnt vmcnt(0)" ::: "memory");
    __builtin_amdgcn_s_barrier();
    __builtin_amdgcn_sched_barrier(0);
    if(t + 3 < nt) stagef(t + 3, (t + 3) & 3);
    const u16* Lb = L[t & 3];
    bf16x8 af[4], bfr[4];
#pragma unroll
    for(int i = 0; i < 4; i++){
      int row = wr * 64 + i * 16 + lr;
      int rh = row >> 1;
      int cph = (lq | ((row & 1) << 2)) ^ (rh & 7);
      af[i] = *(const bf16x8*)&Lb[rh * 64 + cph * 8];
    }
#pragma unroll
    for(int j = 0; j < 4; j++){
      int row = wc * 64 + j * 16 + lr;
      int rh = row >> 1;
      int cph = (lq | ((row & 1) << 2)) ^ (rh & 7);
      bfr[j] = *(const bf16x8*)&Lb[4096 + rh * 64 + cph * 8];
    }
#pragma unroll
    for(int i = 0; i < 4; i++)
#pragma unroll
      for(int j = 0; j < 4; j++)
        acc[i][j] = __builtin_amdgcn_mfma_f32_16x16x32_bf16(af[i], bfr[j], acc[i][j], 0, 0, 0);
  }
#pragma unroll
  for(int i = 0; i < 4; i++)
#pragma unroll
    for(int j = 0; j < 4; j++)
#pragma unroll
      for(int r = 0; r < 4; r++){
        int row = bx * 128 + wr * 64 + i * 16 + lq * 4 + r;
        int col = by * 128 + wc * 64 + j * 16 + lr;
        out[(size_t)row * N + col] = acc[i][j][r];
      }
}

// ---------------- state_chunk (round-10 verbatim) ----------------
__global__ __launch_bounds__(256) void state_chunk(
    const u16* __restrict__ Kb, const u16* __restrict__ Vb,
    u16* __restrict__ VT, float* __restrict__ Sc)
{
  int bh = blockIdx.x, c = blockIdx.y;
  int b = bh >> 4, h = bh & 15;
  int tid = threadIdx.x;
  __shared__ u16 Kt[128][72];
  __shared__ u16 Vt[128][72];
  __shared__ u16 KtT[64][136];
  __shared__ u16 VtT[64][136];
  int rr = tid >> 3;
  int cc = (tid & 7) * 8;
  const u16* kg = Kb + (size_t)(b * 2048 + c * 128) * 1024 + h * 64;
  const u16* vg = Vb + (size_t)(b * 2048 + c * 128) * 1024 + h * 64;
#pragma unroll
  for(int p = 0; p < 4; p++){
    int row = rr + p * 32;
    *(int4*)&Kt[row][cc] = *(const int4*)(kg + (size_t)row * 1024 + cc);
    *(int4*)&Vt[row][cc] = *(const int4*)(vg + (size_t)row * 1024 + cc);
  }
  __syncthreads();
  int d = tid >> 2, tseg = (tid & 3) * 32;
#pragma unroll
  for(int j = 0; j < 32; j += 8){
    u16 tk[8] __attribute__((aligned(16)));
    u16 tv[8] __attribute__((aligned(16)));
#pragma unroll
    for(int q = 0; q < 8; q++){
      tk[q] = Kt[tseg + j + q][d];
      tv[q] = Vt[tseg + j + q][d];
    }
    *(int4*)&KtT[d][tseg + j] = *(const int4*)tk;
    *(int4*)&VtT[d][tseg + j] = *(const int4*)tv;
  }
  __syncthreads();
  {
    u16* vto = VT + (size_t)bh * 64 * 2048 + (size_t)d * 2048 + c * 128 + tseg;
#pragma unroll
    for(int j = 0; j < 32; j += 8)
      *(int4*)(vto + j) = *(const int4*)&VtT[d][tseg + j];
  }
  int wid = tid >> 6, lane = tid & 63;
  int wr = wid >> 1, wc = wid & 1;
  int lr = lane & 15, lk8 = (lane >> 4) * 8, lq = lane >> 4;
  f32x4 acc[2][2] = {};
#pragma unroll
  for(int ks = 0; ks < 4; ks++){
    bf16x8 a[2], bb[2];
#pragma unroll
    for(int i = 0; i < 2; i++) a[i]  = *(const bf16x8*)&VtT[wr * 32 + i * 16 + lr][ks * 32 + lk8];
#pragma unroll
    for(int j = 0; j < 2; j++) bb[j] = *(const bf16x8*)&KtT[wc * 32 + j * 16 + lr][ks * 32 + lk8];
#pragma unroll
    for(int i = 0; i < 2; i++)
#pragma unroll
      for(int j = 0; j < 2; j++)
        acc[i][j] = __builtin_amdgcn_mfma_f32_16x16x32_bf16(a[i], bb[j], acc[i][j], 0, 0, 0);
  }
  float* out = Sc + ((size_t)bh * 16 + c) * 4096;
#pragma unroll
  for(int i = 0; i < 2; i++)
#pragma unroll
    for(int j = 0; j < 2; j++)
#pragma unroll
      for(int r = 0; r < 4; r++){
        int e = wr * 32 + i * 16 + lq * 4 + r, dk = wc * 32 + j * 16 + lr;
        out[e * 64 + dk] = acc[i][j][r];
      }
}

// ---------------- prefix + fold (fold computes Bm inline, cvt Wc in-reg) ----------------
__global__ __launch_bounds__(256) void prefix_fold(
    const float* __restrict__ Sc, u16* __restrict__ Scb,
    const float* __restrict__ Wc, const float* __restrict__ Ltri, u16* __restrict__ Wcpb)
{
  if(blockIdx.x >= 128){
    __shared__ float Lm[64][65];
    __shared__ float Bmf[64][64];
    int ob = blockIdx.x - 128;
    int rt = ob & 7, h = ob >> 3;
    int tid = threadIdx.x;
    const float* src = Ltri + (size_t)h * 4096;
    for(int i = tid; i < 4096; i += 256){
      int e = i >> 6, k = i & 63;
      Lm[e][k] = (k <= e) ? src[i] : 0.f;
    }
    __syncthreads();
    for(int i = tid; i < 4096; i += 256){
      int e = i >> 6, dk = i & 63;
      float sum = 0.f;
      int kmax = e < dk ? e : dk;
      for(int k = 0; k <= kmax; k++) sum += Lm[e][k] * Lm[dk][k];
      Bmf[e][dk] = sum;
    }
    __syncthreads();
    int wid = tid >> 6, lane = tid & 63;
    int lr = lane & 15, lk8 = (lane >> 4) * 8, lq = lane >> 4;
    const float* ab = Wc + (size_t)(rt * 128) * 1024 + h * 64;
    f32x4 acc[2][4] = {};
#pragma unroll
    for(int i = 0; i < 2; i++){
      int mf = wid * 2 + i;
#pragma unroll
      for(int ks = 0; ks < 2; ks++){
        const float* ar = ab + (size_t)(mf * 16 + lr) * 1024 + ks * 32 + lk8;
        u16 ha[8] __attribute__((aligned(16)));
#pragma unroll
        for(int q = 0; q < 8; q++) ha[q] = f2bf(ar[q]);
        bf16x8 a = *(const bf16x8*)ha;
#pragma unroll
        for(int nf = 0; nf < 4; nf++){
          const float* br = &Bmf[nf * 16 + lr][ks * 32 + lk8];
          u16 hb[8] __attribute__((aligned(16)));
#pragma unroll
          for(int q = 0; q < 8; q++) hb[q] = f2bf(br[q]);
          bf16x8 b = *(const bf16x8*)hb;
          acc[i][nf] = __builtin_amdgcn_mfma_f32_16x16x32_bf16(a, b, acc[i][nf], 0, 0, 0);
        }
      }
    }
#pragma unroll
    for(int i = 0; i < 2; i++)
#pragma unroll
      for(int nf = 0; nf < 4; nf++)
#pragma unroll
        for(int r = 0; r < 4; r++){
          int row = rt * 128 + (wid * 2 + i) * 16 + lq * 4 + r;
          int col = h * 64 + nf * 16 + lr;
          Wcpb[(size_t)row * 1024 + col] = f2bf(acc[i][nf][r]);
        }
    return;
  }
  int bh = blockIdx.x >> 2, part = blockIdx.x & 3;
  int e4 = part * 256 + threadIdx.x;
  const float4* s = (const float4*)(Sc + (size_t)bh * 65536) + e4;
  u16* d = Scb + (size_t)bh * 65536 + e4 * 4;
  float4 run = {0.f, 0.f, 0.f, 0.f};
  for(int c = 0; c < 16; c++){
    float4 v = s[(size_t)c * 1024];
    u64 pk = (u64)f2bf(run.x) | ((u64)f2bf(run.y) << 16) | ((u64)f2bf(run.z) << 32) | ((u64)f2bf(run.w) << 48);
    *(u64*)(d + (size_t)c * 4096) = pk;
    run.x += v.x; run.y += v.y; run.z += v.z; run.w += v.w;
  }
}

// ---------------- chunk_attn (round-10 verbatim) ----------------
__global__ __launch_bounds__(256) void chunk_attn(
    const u16* __restrict__ Q, const u16* __restrict__ Kmat,
    const u16* __restrict__ VT, const u16* __restrict__ Scb, u16* __restrict__ Y)
{
  int bh = blockIdx.x, c = blockIdx.y;
  int b = bh >> 4, h = bh & 15;
  int t = threadIdx.x, wid = t >> 6, lane = t & 63;
  int lr = lane & 15, lk8 = (lane >> 4) * 8, lq = lane >> 4;
  __shared__ u16 S[128 * 128];
  const u16* qg = Q    + (size_t)(b * 2048 + c * 128) * 1024 + h * 64;
  const u16* kg = Kmat + (size_t)(b * 2048 + c * 128) * 1024 + h * 64;
  const u16* scb = Scb + ((size_t)bh * 16 + c) * 4096;
  const u16* vt  = VT + (size_t)bh * 64 * 2048 + (size_t)c * 128;
  u16* yg = Y + (size_t)(b * 2048 + c * 128) * 1024 + h * 64;

  bf16x8 a[2][2];
#pragma unroll
  for(int mi = 0; mi < 2; mi++){
    int mf = wid + mi * 4;
    int Rm = mf * 16;
    if((mf & 1) == 0){
      int zr = Rm + (lane >> 2), zc = Rm + 16 + (lane & 3) * 4;
      int zoff = ((zr * 128 + zc) * 2) ^ ((zr & 7) << 4);
      *(u64*)((char*)S + zoff) = 0ULL;
    }
#pragma unroll
    for(int ks = 0; ks < 2; ks++) a[mi][ks] = *(const bf16x8*)(qg + (size_t)(Rm + lr) * 1024 + ks * 32 + lk8);
    for(int nf = 0; nf <= mf; nf++){
      f32x4 acc = {};
#pragma unroll
      for(int ks = 0; ks < 2; ks++){
        bf16x8 bb = *(const bf16x8*)(kg + (size_t)(nf * 16 + lr) * 1024 + ks * 32 + lk8);
        acc = __builtin_amdgcn_mfma_f32_16x16x32_bf16(a[mi][ks], bb, acc, 0, 0, 0);
      }
#pragma unroll
      for(int r = 0; r < 4; r++){
        int row = lq * 4 + r, col = lr;
        float v = acc[r];
        if(nf == mf && col > row) v = 0.f;
        int grow = Rm + row, gcol = nf * 16 + col;
        int off = ((grow * 128 + gcol) * 2) ^ ((grow & 7) << 4);
        *(u16*)((char*)S + off) = f2bf(v);
      }
    }
  }
  f32x4 acc2[2][4] = {};
#pragma unroll
  for(int nf = 0; nf < 4; nf++)
#pragma unroll
    for(int ks = 0; ks < 2; ks++){
      bf16x8 bb = *(const bf16x8*)(scb + (nf * 16 + lr) * 64 + ks * 32 + lk8);
#pragma unroll
      for(int mi = 0; mi < 2; mi++)
        acc2[mi][nf] = __builtin_amdgcn_mfma_f32_16x16x32_bf16(a[mi][ks], bb, acc2[mi][nf], 0, 0, 0);
    }
  int ks0 = wid >> 1;
  int row0 = wid * 16 + lr;
  int row1 = (wid + 4) * 16 + lr;
  for(int ks = 0; ks <= ks0 + 2; ks++){
    bf16x8 bb[4];
#pragma unroll
    for(int nf = 0; nf < 4; nf++)
      bb[nf] = *(const bf16x8*)(vt + (size_t)(nf * 16 + lr) * 2048 + ks * 32 + lk8);
    if(ks <= ks0){
      int off = ((row0 * 128 + ks * 32 + lk8) * 2) ^ ((row0 & 7) << 4);
      bf16x8 af = *(const bf16x8*)((char*)S + off);
#pragma unroll
      for(int nf = 0; nf < 4; nf++)
        acc2[0][nf] = __builtin_amdgcn_mfma_f32_16x16x32_bf16(af, bb[nf], acc2[0][nf], 0, 0, 0);
    }
    {
      int off = ((row1 * 128 + ks * 32 + lk8) * 2) ^ ((row1 & 7) << 4);
      bf16x8 af = *(const bf16x8*)((char*)S + off);
#pragma unroll
      for(int nf = 0; nf < 4; nf++)
        acc2[1][nf] = __builtin_amdgcn_mfma_f32_16x16x32_bf16(af, bb[nf], acc2[1][nf], 0, 0, 0);
    }
  }
#pragma unroll
  for(int mi = 0; mi < 2; mi++){
    int Rm = (wid + mi * 4) * 16;
#pragma unroll
    for(int nf = 0; nf < 4; nf++)
#pragma unroll
      for(int r = 0; r < 4; r++){
        int grow = Rm + lq * 4 + r, gcol = nf * 16 + lr;
        yg[(size_t)grow * 1024 + gcol] = f2bf(acc2[mi][nf][r]);
      }
  }
}

// ---------------- launch ----------------
extern "C" void kernel_launch(void* const* d_in, const int* in_sizes, int n_in,
                              void* d_out, int out_size, void* d_ws, size_t ws_size,
                              hipStream_t stream)
{
  const float* X    = (const float*)d_in[0];
  const float* Wq   = (const float*)d_in[1];
  const float* Wk   = (const float*)d_in[2];
  const float* Wv   = (const float*)d_in[3];
  const float* Wc   = (const float*)d_in[4];
  const float* Ltri = (const float*)d_in[5];
  float* out = (float*)d_out;

  char* ws = (char*)d_ws;
  size_t off = 0;
  auto carve = [&](size_t bytes) -> char* {
    char* p = ws + off;
    off += (bytes + 255) & ~(size_t)255;
    return p;
  };
  u16* Qb   = (u16*)carve((size_t)4194304 * 2);
  u16* Kb   = (u16*)carve((size_t)4194304 * 2);
  u16* Vb   = (u16*)carve((size_t)4194304 * 2);
  u16* VT   = (u16*)carve((size_t)4194304 * 2);
  float* Sc = (float*)carve((size_t)2097152 * 4);
  u16* Scb  = (u16*)carve((size_t)2097152 * 2);
  u16* Wcpb = (u16*)carve((size_t)1048576 * 2);
  u16* Yb   = (u16*)carve((size_t)4194304 * 2);
  (void)in_sizes; (void)n_in; (void)out_size; (void)ws_size;

  qkv_gemm<<<dim3(32, 24), 256, 0, stream>>>(X, Wq, Wk, Wv, Qb, Kb, Vb);
  state_chunk<<<dim3(32, 16), 256, 0, stream>>>(Kb, Vb, VT, Sc);
  prefix_fold<<<256, 256, 0, stream>>>(Sc, Scb, Wc, Ltri, Wcpb);
  chunk_attn<<<dim3(32, 16), 256, 0, stream>>>(Qb, Kb, VT, Scb, Yb);
  out_gemm<<<dim3(32, 8), 256, 0, stream>>>(Yb, Wcpb, out);
}